// Round 9
// baseline (266.914 us; speedup 1.0000x reference)
//
#include <hip/hip_runtime.h>

// GeneralizedHamiltonianDynamics: bf16 MFMA pipeline
// B=32768, DIN=64, HID=1024
// K0a: W2 pack (coalesced LDS transpose); K0b: small weight packs
// K1:  h1 = tanh(z@W1+b1)             -> ws (bf16)
// K2:  gpre2 = W3*(1-tanh^2(h1@W2+b2)) -> ws (bf16)  [256^2 BK=32 GEMM, 2 blocks/CU]
// K3:  gpre1 = (gpre2@W2^T)*(1-h1^2)  -> in-place over h1 (bf16)  [same GEMM]
// K1f: f1 = tanh(z@Wf1+bf1) -> gp2 buffer (free after K3)
// K4:  out = [gp1|f1] @ [W1s|Wf2p]^T + bf2  (8-wave K-split streaming GEMM)

typedef __attribute__((ext_vector_type(8))) short s16x8;
typedef __attribute__((ext_vector_type(4))) float f32x4;
typedef unsigned short u16;

#define DEVFN static __device__ __forceinline__

constexpr int DIN = 64;
constexpr int HID = 1024;

DEVFN u16 f2bf(float f) {
  unsigned u = __builtin_bit_cast(unsigned, f);
  u += 0x7fffu + ((u >> 16) & 1u);   // round-to-nearest-even
  return (u16)(u >> 16);
}
DEVFN float bf2f(u16 h) {
  unsigned u = ((unsigned)h) << 16;
  return __builtin_bit_cast(float, u);
}
DEVFN float fast_tanh(float x) {
  float e = __builtin_amdgcn_exp2f(x * 2.8853900817779268f);
  return 1.0f - 2.0f * __builtin_amdgcn_rcpf(e + 1.0f);
}
DEVFN f32x4 mfma16(s16x8 a, s16x8 b, f32x4 c) {
  return __builtin_amdgcn_mfma_f32_16x16x32_bf16(a, b, c, 0, 0, 0);
}

#define GLOAD16(g, l) __builtin_amdgcn_global_load_lds( \
    (const __attribute__((address_space(1))) unsigned int*)(const void*)(g), \
    (__attribute__((address_space(3))) unsigned int*)(void*)(l), 16, 0, 0)

// ---------------- K0a: W2 pack via coalesced LDS transpose ----------------
__global__ __launch_bounds__(256) void k0_w2(const float* __restrict__ W2,
                                             u16* __restrict__ W2tp, u16* __restrict__ W2c) {
  __shared__ u16 tl[64 * 65];
  const int bi = blockIdx.x >> 4, bj = blockIdx.x & 15;
  const int tid = threadIdx.x;
#pragma unroll
  for (int i = 0; i < 16; ++i) {
    int idx = i * 256 + tid;           // 0..4095
    int r = idx >> 6, c = idx & 63;
    float v = W2[(size_t)(bi * 64 + r) * 1024 + bj * 64 + c];
    u16 b = f2bf(v);
    W2c[(size_t)(bi * 64 + r) * 1024 + bj * 64 + c] = b;
    tl[r * 65 + c] = b;
  }
  __syncthreads();
#pragma unroll
  for (int i = 0; i < 16; ++i) {
    int idx = i * 256 + tid;
    int r = idx >> 6, c = idx & 63;    // output row (n), col (k)
    W2tp[(size_t)(bj * 64 + r) * 1024 + bi * 64 + c] = tl[c * 65 + r];
  }
}

// ---------------- K0b: small weight packs ----------------
__global__ __launch_bounds__(256) void k0_small(
    const float* W1, const float* Wf1, const float* Wf2,
    u16* W1p, u16* Wf1p, u16* W1s, u16* Wf2p) {
  int id = blockIdx.x * 256 + threadIdx.x;   // < 65536
  int n = id >> 6, k = id & 63;
  W1p[id]  = f2bf(W1[k * HID + n]);
  Wf1p[id] = f2bf(Wf1[k * HID + n]);
  int nn = id >> 10, kk2 = id & 1023;
  float s = (nn < 32) ? 1.f : -1.f;
  W1s[id]  = f2bf(s * W1[((nn + 32) & 63) * HID + kk2]);
  Wf2p[id] = f2bf(Wf2[kk2 * DIN + nn]);
}

// ---------------- K1: out = tanh(z@Wp + b) ---------------- (used for h1 AND f1)
__global__ __launch_bounds__(256) void k1_h1(const float* z, const u16* Wp,
                                             const float* b, u16* o) {
  __shared__ __align__(16) u16 zl[64 * 72];
  const int tid = threadIdx.x;
  const int lane = tid & 63, w = tid >> 6;
  const int nb = blockIdx.x & 7, mb = blockIdx.x >> 3;
  const size_t m0 = (size_t)mb * 64;
  const int n0 = nb * 128;
#pragma unroll
  for (int c = 0; c < 4; ++c) {
    int i4 = c * 256 + tid;
    int row = i4 >> 4, col4 = (i4 & 15) * 4;
    f32x4 v = *reinterpret_cast<const f32x4*>(z + (m0 + row) * DIN + col4);
    u16* d = zl + row * 72 + col4;
    d[0] = f2bf(v[0]); d[1] = f2bf(v[1]); d[2] = f2bf(v[2]); d[3] = f2bf(v[3]);
  }
  __syncthreads();
  f32x4 acc[8] = {};
#pragma unroll
  for (int kk = 0; kk < 2; ++kk) {
    const int karr = kk * 32 + ((lane >> 4) << 3);
    s16x8 a = *reinterpret_cast<const s16x8*>(zl + (16 * w + (lane & 15)) * 72 + karr);
#pragma unroll
    for (int fn = 0; fn < 8; ++fn) {
      int n = n0 + fn * 16 + (lane & 15);
      s16x8 bb = *reinterpret_cast<const s16x8*>(Wp + (size_t)n * 64 + karr);
      acc[fn] = mfma16(a, bb, acc[fn]);
    }
  }
#pragma unroll
  for (int fn = 0; fn < 8; ++fn) {
    int n = n0 + fn * 16 + (lane & 15);
    float bias = b[n];
#pragma unroll
    for (int j = 0; j < 4; ++j) {
      size_t m = m0 + 16 * w + ((lane >> 4) << 2) + j;
      o[m * HID + n] = f2bf(fast_tanh(acc[fn][j] + bias));
    }
  }
}

// ---------------- K2/K3: 256x256-tile BK=32 pipelined GEMM ----------------
// 8 waves (2M x 4N), BK=32, double-buffered 64KB LDS -> 2 blocks/CU.
// Same 2-phase counted-vmcnt discipline as the proven BK=64 version;
// vmcnt(2) retires exactly the prior tile's A+B. 64B row stride -> natural
// 2-way bank aliasing (free), no swizzle, linear staging source.
template <int MODE>
__global__ __launch_bounds__(512, 2) void k23_gemm(
    const u16* __restrict__ A, const u16* __restrict__ Bp,
    const float* __restrict__ b2, const float* __restrict__ W3,
    const u16* __restrict__ h1in, u16* __restrict__ outb) {
  extern __shared__ u16 lds[];  // 2 bufs x (A[256][32] + B[256][32]) = 32768 u16
  const int tid = threadIdx.x;
  const int lane = tid & 63, w = tid >> 6;
  const int wr = w >> 2, wc = w & 3;
  const int xcd = blockIdx.x & 7, local = blockIdx.x >> 3;
  const size_t m0 = (size_t)(xcd * 16 + (local >> 2)) * 256;
  const int n0 = (local & 3) * 256;

  const u16* gpa[2]; const u16* gpb[2]; int lo[2];
#pragma unroll
  for (int c = 0; c < 2; ++c) {
    int idx = c * 512 + tid, row = idx >> 2, cg = idx & 3;
    gpa[c] = A + (m0 + row) * 1024 + cg * 8;
    gpb[c] = Bp + (size_t)(n0 + row) * 1024 + cg * 8;
    lo[c] = idx * 8;
  }
#define STAGE_A(B_, T_) { _Pragma("unroll") for (int c = 0; c < 2; ++c) \
    GLOAD16(gpa[c] + (T_) * 32, lds + (B_) * 16384 + lo[c]); }
#define STAGE_B(B_, T_) { _Pragma("unroll") for (int c = 0; c < 2; ++c) \
    GLOAD16(gpb[c] + (T_) * 32, lds + (B_) * 16384 + 8192 + lo[c]); }

  const int lr15 = lane & 15, g = lane >> 4;
  int aoff[8], boff[4];
#pragma unroll
  for (int i = 0; i < 8; ++i)
    aoff[i] = (wr * 128 + i * 16 + lr15) * 32 + g * 8;
#pragma unroll
  for (int j = 0; j < 4; ++j)
    boff[j] = (wc * 64 + j * 16 + lr15) * 32 + g * 8;

  f32x4 acc[8][4] = {};
  s16x8 af[4], bf[4];

#define LDB(B_) { _Pragma("unroll") for (int j = 0; j < 4; ++j) \
    bf[j] = *reinterpret_cast<const s16x8*>(lds + (B_) * 16384 + 8192 + boff[j]); }
#define LDA(B_, H_) { _Pragma("unroll") for (int i = 0; i < 4; ++i) \
    af[i] = *reinterpret_cast<const s16x8*>(lds + (B_) * 16384 + aoff[(H_) * 4 + i]); }
#define MMH(H_) { __builtin_amdgcn_s_setprio(1); \
    _Pragma("unroll") for (int i = 0; i < 4; ++i) { \
      _Pragma("unroll") for (int j = 0; j < 4; ++j) \
        acc[(H_) * 4 + i][j] = mfma16(af[i], bf[j], acc[(H_) * 4 + i][j]); } \
    __builtin_amdgcn_s_setprio(0); }

  STAGE_A(0, 0); STAGE_B(0, 0);
  for (int t = 0; t < 31; ++t) {
    const int cur = t & 1, nxt = cur ^ 1;
    STAGE_A(nxt, t + 1);
    asm volatile("s_waitcnt vmcnt(2)" ::: "memory");
    __builtin_amdgcn_s_barrier();
    asm volatile("" ::: "memory");
    LDB(cur); LDA(cur, 0);
    MMH(0);
    STAGE_B(nxt, t + 1);
    LDA(cur, 1);
    MMH(1);
    asm volatile("" ::: "memory");
    __builtin_amdgcn_s_barrier();
    asm volatile("" ::: "memory");
  }
  asm volatile("s_waitcnt vmcnt(0)" ::: "memory");
  __builtin_amdgcn_s_barrier();
  asm volatile("" ::: "memory");
  LDB(1); LDA(1, 0);
  MMH(0);
  LDA(1, 1);
  MMH(1);
  asm volatile("" ::: "memory");
  __builtin_amdgcn_s_barrier();          // LDS now reusable for epilogue
  asm volatile("" ::: "memory");

  // Epilogue: repack through wave-private 8KB LDS region -> coalesced 16B stores
  const int wbase = w * 4096;
  float b2v[4], w3v[4];
  if (MODE == 0) {
#pragma unroll
    for (int j = 0; j < 4; ++j) {
      int n = n0 + wc * 64 + j * 16 + (lane & 15);
      b2v[j] = b2[n]; w3v[j] = W3[n];
    }
  }
#pragma unroll
  for (int h = 0; h < 2; ++h) {
    if (h == 1) asm volatile("s_waitcnt lgkmcnt(0)" ::: "memory");
#pragma unroll
    for (int ip = 0; ip < 4; ++ip) {
#pragma unroll
      for (int j = 0; j < 4; ++j) {
#pragma unroll
        for (int r = 0; r < 4; ++r) {
          float v = acc[h * 4 + ip][j][r];
          u16 o;
          if (MODE == 0) {
            float tt = fast_tanh(v + b2v[j]);
            o = f2bf(w3v[j] * (1.f - tt * tt));
          } else {
            o = f2bf(v);
          }
          int lr = ip * 16 + ((lane >> 4) << 2) + r;
          lds[wbase + lr * 64 + j * 16 + (lane & 15)] = o;
        }
      }
    }
#pragma unroll
    for (int r8 = 0; r8 < 8; ++r8) {
      int lr = r8 * 8 + (lane >> 3), c8 = (lane & 7) * 8;
      s16x8 vv = *reinterpret_cast<const s16x8*>(lds + wbase + lr * 64 + c8);
      size_t grow = m0 + wr * 128 + h * 64 + lr;
      int gcol = n0 + wc * 64 + c8;
      if (MODE == 1) {
        s16x8 hh = *reinterpret_cast<const s16x8*>(h1in + grow * 1024 + gcol);
#pragma unroll
        for (int e = 0; e < 8; ++e) {
          float hv = bf2f((u16)hh[e]);
          vv[e] = (short)f2bf(bf2f((u16)vv[e]) * (1.f - hv * hv));
        }
      }
      *reinterpret_cast<s16x8*>(outb + grow * 1024 + gcol) = vv;
    }
  }
#undef STAGE_A
#undef STAGE_B
#undef LDB
#undef LDA
#undef MMH
}

// ---------------- K4 v5b: 8-wave K-split streaming GEMM (ko_ bug fixed) -------
// out[m][n] = sum_{k<2048} Acat[m][k]*Bcat[n][k] + bf2[n]
// 512 threads = 2 groups x 4 waves. Group 0: gp1 x W1s (its k-tiles 0-15);
// group 1: f1 x Wf2p (its local k-tiles 0-15). Each group runs the proven
// double-buffered vmcnt(4) loop independently; LDS reduce at end.
// 64 KB LDS, 2 blocks/CU -> 4 waves/SIMD (2x TLP vs v2/v4).
__global__ __launch_bounds__(512) void k4_gemm(
    const u16* __restrict__ gp1, const u16* __restrict__ f1,
    const u16* __restrict__ W1s, const u16* __restrict__ Wf2p,
    const float* __restrict__ bf2, float* __restrict__ out) {
  __shared__ __align__(16) u16 Ab[2][2][4096];   // [grp][buf][64x64] swizzled
  __shared__ __align__(16) u16 Bb[2][2][4096];
  const int tid = threadIdx.x;
  const int w8 = tid >> 6, lane = tid & 63;
  const int grp = w8 >> 2, w = w8 & 3;
  const int gt = tid & 255;
  const int lr = lane & 15, g = lane >> 4;
  const size_t m0 = (size_t)blockIdx.x * 64;
  const u16* asrc = grp ? f1 : gp1;      // each buffer is [32768][1024]
  const u16* bsrc = grp ? Wf2p : W1s;    // each is [64][1024]

  int aoffs[2], boffs[2], lo[2];
#pragma unroll
  for (int c = 0; c < 2; ++c) {
    int idx = c * 256 + gt;           // 0..511 16B-chunks per tile
    int row = idx >> 3, cg = idx & 7;
    aoffs[c] = (int)((m0 + row) * 1024) + ((cg ^ (row & 7)) << 3);
    boffs[c] = row * 1024 + ((cg ^ (row & 7)) << 3);
    lo[c] = idx * 8;
  }
  // LOCAL k-offset within the group's own source (fix of the r8 bug: no +16)
#define K4STAGE(B_, T_) { const int ko_ = (T_) * 64; \
    _Pragma("unroll") for (int c = 0; c < 2; ++c) { \
      GLOAD16(asrc + aoffs[c] + ko_, Ab[grp][B_] + lo[c]); \
      GLOAD16(bsrc + boffs[c] + ko_, Bb[grp][B_] + lo[c]); } }

  const int arow = w * 16 + lr;
  int afr[2], bfr[2][4];
#pragma unroll
  for (int kkl = 0; kkl < 2; ++kkl) {
    afr[kkl] = arow * 64 + ((kkl * 32 + g * 8) ^ ((arow & 7) << 3));
#pragma unroll
    for (int fn = 0; fn < 4; ++fn) {
      int br = fn * 16 + lr;
      bfr[kkl][fn] = br * 64 + ((kkl * 32 + g * 8) ^ ((br & 7) << 3));
    }
  }

  f32x4 acc[4] = {};
#define K4MM(BUF_) { \
    _Pragma("unroll") for (int kkl = 0; kkl < 2; ++kkl) { \
      s16x8 a = *reinterpret_cast<const s16x8*>(Ab[grp][BUF_] + afr[kkl]); \
      _Pragma("unroll") for (int fn = 0; fn < 4; ++fn) { \
        s16x8 b = *reinterpret_cast<const s16x8*>(Bb[grp][BUF_] + bfr[kkl][fn]); \
        acc[fn] = mfma16(a, b, acc[fn]); } } }
#define TBAR() { asm volatile("" ::: "memory"); __builtin_amdgcn_s_barrier(); asm volatile("" ::: "memory"); }

  K4STAGE(0, 0);
  for (int t = 0; t < 15; ++t) {
    K4STAGE((t + 1) & 1, t + 1);
    asm volatile("s_waitcnt vmcnt(4)" ::: "memory"); // retire tile t's 4 loads
    TBAR();
    K4MM(t & 1);
    TBAR();
  }
  asm volatile("s_waitcnt vmcnt(0)" ::: "memory");
  TBAR();
  K4MM(1);

  // cross-group reduction through LDS (reuse Ab as 16KB float buffer)
  __syncthreads();
  float* red = (float*)&Ab[0][0][0];
  if (grp == 1) {
#pragma unroll
    for (int fn = 0; fn < 4; ++fn)
#pragma unroll
      for (int j = 0; j < 4; ++j)
        red[(fn * 4 + j) * 256 + gt] = acc[fn][j];
  }
  __syncthreads();
  if (grp == 0) {
#pragma unroll
    for (int fn = 0; fn < 4; ++fn) {
      int n = fn * 16 + lr;
      float bias = bf2[n];
#pragma unroll
      for (int j = 0; j < 4; ++j) {
        float v = acc[fn][j] + red[(fn * 4 + j) * 256 + gt] + bias;
        size_t m = m0 + w * 16 + g * 4 + j;
        out[m * DIN + n] = v;
      }
    }
  }
#undef K4STAGE
#undef K4MM
#undef TBAR
}

extern "C" void kernel_launch(void* const* d_in, const int* in_sizes, int n_in,
                              void* d_out, int out_size, void* d_ws, size_t ws_size,
                              hipStream_t stream) {
  const float* z   = (const float*)d_in[0];
  const float* W1  = (const float*)d_in[1];
  const float* b1  = (const float*)d_in[2];
  const float* W2  = (const float*)d_in[3];
  const float* b2  = (const float*)d_in[4];
  const float* W3  = (const float*)d_in[5];
  const float* Wf1 = (const float*)d_in[7];
  const float* bf1 = (const float*)d_in[8];
  const float* Wf2 = (const float*)d_in[9];
  const float* bf2 = (const float*)d_in[10];

  char* ws = (char*)d_ws;
  u16* W1p  = (u16*)(ws + 0);          // 128KB
  u16* Wf1p = (u16*)(ws + 131072);     // 128KB
  u16* W2tp = (u16*)(ws + 262144);     // 2MB
  u16* W2c  = (u16*)(ws + 2359296);    // 2MB
  u16* W1s  = (u16*)(ws + 4456448);    // 128KB (symplectic-folded W1)
  u16* Wf2p = (u16*)(ws + 4587520);    // 128KB
  u16* h1   = (u16*)(ws + 4718592);    // 64MB (becomes gpre1 in-place after K3)
  u16* gp2  = (u16*)(ws + 4718592 + 67108864);  // 64MB (becomes f1 after K1f)
  float* out = (float*)d_out;

  k0_w2<<<256, 256, 0, stream>>>(W2, W2tp, W2c);
  k0_small<<<256, 256, 0, stream>>>(W1, Wf1, Wf2, W1p, Wf1p, W1s, Wf2p);
  k1_h1<<<4096, 256, 0, stream>>>(z, W1p, b1, h1);
  k23_gemm<0><<<512, 512, 65536, stream>>>(h1, W2tp, b2, W3, nullptr, gp2);
  k23_gemm<1><<<512, 512, 65536, stream>>>(gp2, W2c, nullptr, nullptr, h1, h1);
  k1_h1<<<4096, 256, 0, stream>>>(z, Wf1p, bf1, gp2);   // f1 -> gp2 buffer
  k4_gemm<<<512, 512, 0, stream>>>(h1, gp2, W1s, Wf2p, bf2, out);
}

// Round 10
// 251.524 us; speedup vs baseline: 1.0612x; 1.0612x over previous
//
#include <hip/hip_runtime.h>

// GeneralizedHamiltonianDynamics: bf16 MFMA pipeline
// B=32768, DIN=64, HID=1024
// K0:  merged weight prep (W2 LDS-transpose pack + small packs)
// K1:  h1 = tanh(z@W1+b1)             -> ws (bf16)
// K2:  gpre2 = W3*(1-tanh^2(h1@W2+b2)) -> ws (bf16)  [256^2 BK=64 GEMM, proven]
// K3:  gpre1 = (gpre2@W2^T)*(1-h1^2)  -> in-place over h1 (bf16)  [same GEMM]
// K1f: f1 = tanh(z@Wf1+bf1) -> gp2 buffer (free after K3)
// K4:  out = [gp1|f1] @ [W1s|Wf2p]^T + bf2  (8-wave K-split streaming GEMM)

typedef __attribute__((ext_vector_type(8))) short s16x8;
typedef __attribute__((ext_vector_type(4))) float f32x4;
typedef unsigned short u16;

#define DEVFN static __device__ __forceinline__

constexpr int DIN = 64;
constexpr int HID = 1024;

DEVFN u16 f2bf(float f) {
  unsigned u = __builtin_bit_cast(unsigned, f);
  u += 0x7fffu + ((u >> 16) & 1u);   // round-to-nearest-even
  return (u16)(u >> 16);
}
DEVFN float bf2f(u16 h) {
  unsigned u = ((unsigned)h) << 16;
  return __builtin_bit_cast(float, u);
}
DEVFN float fast_tanh(float x) {
  float e = __builtin_amdgcn_exp2f(x * 2.8853900817779268f);
  return 1.0f - 2.0f * __builtin_amdgcn_rcpf(e + 1.0f);
}
DEVFN f32x4 mfma16(s16x8 a, s16x8 b, f32x4 c) {
  return __builtin_amdgcn_mfma_f32_16x16x32_bf16(a, b, c, 0, 0, 0);
}

#define GLOAD16(g, l) __builtin_amdgcn_global_load_lds( \
    (const __attribute__((address_space(1))) unsigned int*)(const void*)(g), \
    (__attribute__((address_space(3))) unsigned int*)(void*)(l), 16, 0, 0)

// ---------------- K0: merged weight prep ----------------
// Per block (256 blocks, 256 threads):
//  (a) one 64x64 W2 tile: W2c = bf16(W2), W2tp = bf16(W2^T) via padded LDS
//  (b) 256 ids of the small packs: W1p/Wf1p [1024][64] = W^T;
//      W1s[64][1024] = sgn(n)*W1[(n+32)&63][k]; Wf2p[64][1024] = Wf2^T
__global__ __launch_bounds__(256) void k0_prep(
    const float* __restrict__ W2, const float* __restrict__ W1,
    const float* __restrict__ Wf1, const float* __restrict__ Wf2,
    u16* __restrict__ W2tp, u16* __restrict__ W2c,
    u16* __restrict__ W1p, u16* __restrict__ Wf1p,
    u16* __restrict__ W1s, u16* __restrict__ Wf2p) {
  __shared__ u16 tl[64 * 65];
  const int bi = blockIdx.x >> 4, bj = blockIdx.x & 15;
  const int tid = threadIdx.x;
#pragma unroll
  for (int i = 0; i < 16; ++i) {
    int idx = i * 256 + tid;           // 0..4095
    int r = idx >> 6, c = idx & 63;
    float v = W2[(size_t)(bi * 64 + r) * 1024 + bj * 64 + c];
    u16 b = f2bf(v);
    W2c[(size_t)(bi * 64 + r) * 1024 + bj * 64 + c] = b;
    tl[r * 65 + c] = b;
  }
  __syncthreads();
#pragma unroll
  for (int i = 0; i < 16; ++i) {
    int idx = i * 256 + tid;
    int r = idx >> 6, c = idx & 63;    // output row (n), col (k)
    W2tp[(size_t)(bj * 64 + r) * 1024 + bi * 64 + c] = tl[c * 65 + r];
  }
  // small packs: one id per thread per block
  int id = blockIdx.x * 256 + tid;     // < 65536
  int n = id >> 6, k = id & 63;
  W1p[id]  = f2bf(W1[k * HID + n]);
  Wf1p[id] = f2bf(Wf1[k * HID + n]);
  int nn = id >> 10, kk2 = id & 1023;
  float s = (nn < 32) ? 1.f : -1.f;
  W1s[id]  = f2bf(s * W1[((nn + 32) & 63) * HID + kk2]);
  Wf2p[id] = f2bf(Wf2[kk2 * DIN + nn]);
}

// ---------------- K1: out = tanh(z@Wp + b) ---------------- (used for h1 AND f1)
__global__ __launch_bounds__(256) void k1_h1(const float* z, const u16* Wp,
                                             const float* b, u16* o) {
  __shared__ __align__(16) u16 zl[64 * 72];
  const int tid = threadIdx.x;
  const int lane = tid & 63, w = tid >> 6;
  const int nb = blockIdx.x & 7, mb = blockIdx.x >> 3;
  const size_t m0 = (size_t)mb * 64;
  const int n0 = nb * 128;
#pragma unroll
  for (int c = 0; c < 4; ++c) {
    int i4 = c * 256 + tid;
    int row = i4 >> 4, col4 = (i4 & 15) * 4;
    f32x4 v = *reinterpret_cast<const f32x4*>(z + (m0 + row) * DIN + col4);
    u16* d = zl + row * 72 + col4;
    d[0] = f2bf(v[0]); d[1] = f2bf(v[1]); d[2] = f2bf(v[2]); d[3] = f2bf(v[3]);
  }
  __syncthreads();
  f32x4 acc[8] = {};
#pragma unroll
  for (int kk = 0; kk < 2; ++kk) {
    const int karr = kk * 32 + ((lane >> 4) << 3);
    s16x8 a = *reinterpret_cast<const s16x8*>(zl + (16 * w + (lane & 15)) * 72 + karr);
#pragma unroll
    for (int fn = 0; fn < 8; ++fn) {
      int n = n0 + fn * 16 + (lane & 15);
      s16x8 bb = *reinterpret_cast<const s16x8*>(Wp + (size_t)n * 64 + karr);
      acc[fn] = mfma16(a, bb, acc[fn]);
    }
  }
#pragma unroll
  for (int fn = 0; fn < 8; ++fn) {
    int n = n0 + fn * 16 + (lane & 15);
    float bias = b[n];
#pragma unroll
    for (int j = 0; j < 4; ++j) {
      size_t m = m0 + 16 * w + ((lane >> 4) << 2) + j;
      o[m * HID + n] = f2bf(fast_tanh(acc[fn][j] + bias));
    }
  }
}

// ---------------- K2/K3: 256x256-tile BK=64 2-phase pipelined GEMM (proven) ---
template <int MODE>
__global__ __launch_bounds__(512, 2) void k23_gemm(
    const u16* __restrict__ A, const u16* __restrict__ Bp,
    const float* __restrict__ b2, const float* __restrict__ W3,
    const u16* __restrict__ h1in, u16* __restrict__ outb) {
  extern __shared__ u16 lds[];  // 2 bufs x (A[256][64] + B[256][64]) = 65536 u16
  const int tid = threadIdx.x;
  const int lane = tid & 63, w = tid >> 6;
  const int wr = w >> 2, wc = w & 3;
  const int xcd = blockIdx.x & 7, local = blockIdx.x >> 3;
  const size_t m0 = (size_t)(xcd * 16 + (local >> 2)) * 256;
  const int n0 = (local & 3) * 256;

  const u16* gpa[4]; const u16* gpb[4]; int lo[4];
#pragma unroll
  for (int c = 0; c < 4; ++c) {
    int idx = c * 512 + tid, row = idx >> 3, cg = idx & 7;
    int sc = (cg ^ (row & 7)) << 3;
    gpa[c] = A + (m0 + row) * 1024 + sc;
    gpb[c] = Bp + (size_t)(n0 + row) * 1024 + sc;
    lo[c] = idx * 8;
  }
#define STAGE_A(B_, T_) { _Pragma("unroll") for (int c = 0; c < 4; ++c) \
    GLOAD16(gpa[c] + (T_) * 64, lds + (B_) * 32768 + lo[c]); }
#define STAGE_B(B_, T_) { _Pragma("unroll") for (int c = 0; c < 4; ++c) \
    GLOAD16(gpb[c] + (T_) * 64, lds + (B_) * 32768 + 16384 + lo[c]); }

  const int swz = (lane & 7) << 3;
  int aoff[8], boff[4];
#pragma unroll
  for (int i = 0; i < 8; ++i)
    aoff[i] = (wr * 128 + i * 16 + (lane & 15)) * 64 + ((lane >> 4) << 3);
#pragma unroll
  for (int j = 0; j < 4; ++j)
    boff[j] = (wc * 64 + j * 16 + (lane & 15)) * 64 + ((lane >> 4) << 3);

  f32x4 acc[8][4] = {};

#define PHASE(B_, KK_) { \
    s16x8 af[8], bf[4]; \
    _Pragma("unroll") for (int i = 0; i < 8; ++i) \
      af[i] = *reinterpret_cast<const s16x8*>(lds + (B_) * 32768 + ((aoff[i] + (KK_) * 32) ^ swz)); \
    _Pragma("unroll") for (int j = 0; j < 4; ++j) \
      bf[j] = *reinterpret_cast<const s16x8*>(lds + (B_) * 32768 + 16384 + ((boff[j] + (KK_) * 32) ^ swz)); \
    __builtin_amdgcn_s_setprio(1); \
    _Pragma("unroll") for (int i = 0; i < 8; ++i) { \
      _Pragma("unroll") for (int j = 0; j < 4; ++j) \
        acc[i][j] = mfma16(af[i], bf[j], acc[i][j]); } \
    __builtin_amdgcn_s_setprio(0); }

  STAGE_A(0, 0); STAGE_B(0, 0);
  for (int t = 0; t < 15; ++t) {
    const int cur = t & 1, nxt = cur ^ 1;
    STAGE_A(nxt, t + 1);
    asm volatile("s_waitcnt vmcnt(4)" ::: "memory");
    __builtin_amdgcn_s_barrier();
    asm volatile("" ::: "memory");
    PHASE(cur, 0);
    STAGE_B(nxt, t + 1);
    PHASE(cur, 1);
    asm volatile("" ::: "memory");
    __builtin_amdgcn_s_barrier();
    asm volatile("" ::: "memory");
  }
  asm volatile("s_waitcnt vmcnt(0)" ::: "memory");
  __builtin_amdgcn_s_barrier();
  asm volatile("" ::: "memory");
  PHASE(1, 0);
  PHASE(1, 1);
  asm volatile("" ::: "memory");
  __builtin_amdgcn_s_barrier();
  asm volatile("" ::: "memory");

  const int wbase = w * 8192;
  float b2v[4], w3v[4];
  if (MODE == 0) {
#pragma unroll
    for (int j = 0; j < 4; ++j) {
      int n = n0 + wc * 64 + j * 16 + (lane & 15);
      b2v[j] = b2[n]; w3v[j] = W3[n];
    }
  }
#pragma unroll
  for (int h = 0; h < 2; ++h) {
    if (h == 1) asm volatile("s_waitcnt lgkmcnt(0)" ::: "memory");
#pragma unroll
    for (int ip = 0; ip < 4; ++ip) {
#pragma unroll
      for (int j = 0; j < 4; ++j) {
#pragma unroll
        for (int r = 0; r < 4; ++r) {
          float v = acc[h * 4 + ip][j][r];
          u16 o;
          if (MODE == 0) {
            float tt = fast_tanh(v + b2v[j]);
            o = f2bf(w3v[j] * (1.f - tt * tt));
          } else {
            o = f2bf(v);
          }
          int lr = ip * 16 + ((lane >> 4) << 2) + r;
          lds[wbase + lr * 64 + j * 16 + (lane & 15)] = o;
        }
      }
    }
#pragma unroll
    for (int r8 = 0; r8 < 8; ++r8) {
      int lr = r8 * 8 + (lane >> 3), c8 = (lane & 7) * 8;
      s16x8 vv = *reinterpret_cast<const s16x8*>(lds + wbase + lr * 64 + c8);
      size_t grow = m0 + wr * 128 + h * 64 + lr;
      int gcol = n0 + wc * 64 + c8;
      if (MODE == 1) {
        s16x8 hh = *reinterpret_cast<const s16x8*>(h1in + grow * 1024 + gcol);
#pragma unroll
        for (int e = 0; e < 8; ++e) {
          float hv = bf2f((u16)hh[e]);
          vv[e] = (short)f2bf(bf2f((u16)vv[e]) * (1.f - hv * hv));
        }
      }
      *reinterpret_cast<s16x8*>(outb + grow * 1024 + gcol) = vv;
    }
  }
#undef STAGE_A
#undef STAGE_B
#undef PHASE
}

// ---------------- K4 v5b: 8-wave K-split streaming GEMM (proven r9) ----------
// out[m][n] = sum_{k<2048} Acat[m][k]*Bcat[n][k] + bf2[n]
// 512 threads = 2 groups x 4 waves. Group 0: gp1 x W1s; group 1: f1 x Wf2p
// (local k-tiles 0-15 each). Double-buffered vmcnt(4) loop; LDS reduce at end.
__global__ __launch_bounds__(512) void k4_gemm(
    const u16* __restrict__ gp1, const u16* __restrict__ f1,
    const u16* __restrict__ W1s, const u16* __restrict__ Wf2p,
    const float* __restrict__ bf2, float* __restrict__ out) {
  __shared__ __align__(16) u16 Ab[2][2][4096];   // [grp][buf][64x64] swizzled
  __shared__ __align__(16) u16 Bb[2][2][4096];
  const int tid = threadIdx.x;
  const int w8 = tid >> 6, lane = tid & 63;
  const int grp = w8 >> 2, w = w8 & 3;
  const int gt = tid & 255;
  const int lr = lane & 15, g = lane >> 4;
  const size_t m0 = (size_t)blockIdx.x * 64;
  const u16* asrc = grp ? f1 : gp1;      // each buffer is [32768][1024]
  const u16* bsrc = grp ? Wf2p : W1s;    // each is [64][1024]

  int aoffs[2], boffs[2], lo[2];
#pragma unroll
  for (int c = 0; c < 2; ++c) {
    int idx = c * 256 + gt;           // 0..511 16B-chunks per tile
    int row = idx >> 3, cg = idx & 7;
    aoffs[c] = (int)((m0 + row) * 1024) + ((cg ^ (row & 7)) << 3);
    boffs[c] = row * 1024 + ((cg ^ (row & 7)) << 3);
    lo[c] = idx * 8;
  }
#define K4STAGE(B_, T_) { const int ko_ = (T_) * 64; \
    _Pragma("unroll") for (int c = 0; c < 2; ++c) { \
      GLOAD16(asrc + aoffs[c] + ko_, Ab[grp][B_] + lo[c]); \
      GLOAD16(bsrc + boffs[c] + ko_, Bb[grp][B_] + lo[c]); } }

  const int arow = w * 16 + lr;
  int afr[2], bfr[2][4];
#pragma unroll
  for (int kkl = 0; kkl < 2; ++kkl) {
    afr[kkl] = arow * 64 + ((kkl * 32 + g * 8) ^ ((arow & 7) << 3));
#pragma unroll
    for (int fn = 0; fn < 4; ++fn) {
      int br = fn * 16 + lr;
      bfr[kkl][fn] = br * 64 + ((kkl * 32 + g * 8) ^ ((br & 7) << 3));
    }
  }

  f32x4 acc[4] = {};
#define K4MM(BUF_) { \
    _Pragma("unroll") for (int kkl = 0; kkl < 2; ++kkl) { \
      s16x8 a = *reinterpret_cast<const s16x8*>(Ab[grp][BUF_] + afr[kkl]); \
      _Pragma("unroll") for (int fn = 0; fn < 4; ++fn) { \
        s16x8 b = *reinterpret_cast<const s16x8*>(Bb[grp][BUF_] + bfr[kkl][fn]); \
        acc[fn] = mfma16(a, b, acc[fn]); } } }
#define TBAR() { asm volatile("" ::: "memory"); __builtin_amdgcn_s_barrier(); asm volatile("" ::: "memory"); }

  K4STAGE(0, 0);
  for (int t = 0; t < 15; ++t) {
    K4STAGE((t + 1) & 1, t + 1);
    asm volatile("s_waitcnt vmcnt(4)" ::: "memory"); // retire tile t's 4 loads
    TBAR();
    K4MM(t & 1);
    TBAR();
  }
  asm volatile("s_waitcnt vmcnt(0)" ::: "memory");
  TBAR();
  K4MM(1);

  // cross-group reduction through LDS (reuse Ab as 16KB float buffer)
  __syncthreads();
  float* red = (float*)&Ab[0][0][0];
  if (grp == 1) {
#pragma unroll
    for (int fn = 0; fn < 4; ++fn)
#pragma unroll
      for (int j = 0; j < 4; ++j)
        red[(fn * 4 + j) * 256 + gt] = acc[fn][j];
  }
  __syncthreads();
  if (grp == 0) {
#pragma unroll
    for (int fn = 0; fn < 4; ++fn) {
      int n = fn * 16 + lr;
      float bias = bf2[n];
#pragma unroll
      for (int j = 0; j < 4; ++j) {
        float v = acc[fn][j] + red[(fn * 4 + j) * 256 + gt] + bias;
        size_t m = m0 + w * 16 + g * 4 + j;
        out[m * DIN + n] = v;
      }
    }
  }
#undef K4STAGE
#undef K4MM
#undef TBAR
}

extern "C" void kernel_launch(void* const* d_in, const int* in_sizes, int n_in,
                              void* d_out, int out_size, void* d_ws, size_t ws_size,
                              hipStream_t stream) {
  const float* z   = (const float*)d_in[0];
  const float* W1  = (const float*)d_in[1];
  const float* b1  = (const float*)d_in[2];
  const float* W2  = (const float*)d_in[3];
  const float* b2  = (const float*)d_in[4];
  const float* W3  = (const float*)d_in[5];
  const float* Wf1 = (const float*)d_in[7];
  const float* bf1 = (const float*)d_in[8];
  const float* Wf2 = (const float*)d_in[9];
  const float* bf2 = (const float*)d_in[10];

  char* ws = (char*)d_ws;
  u16* W1p  = (u16*)(ws + 0);          // 128KB
  u16* Wf1p = (u16*)(ws + 131072);     // 128KB
  u16* W2tp = (u16*)(ws + 262144);     // 2MB
  u16* W2c  = (u16*)(ws + 2359296);    // 2MB
  u16* W1s  = (u16*)(ws + 4456448);    // 128KB (symplectic-folded W1)
  u16* Wf2p = (u16*)(ws + 4587520);    // 128KB
  u16* h1   = (u16*)(ws + 4718592);    // 64MB (becomes gpre1 in-place after K3)
  u16* gp2  = (u16*)(ws + 4718592 + 67108864);  // 64MB (becomes f1 after K1f)
  float* out = (float*)d_out;

  k0_prep<<<256, 256, 0, stream>>>(W2, W1, Wf1, Wf2, W2tp, W2c, W1p, Wf1p, W1s, Wf2p);
  k1_h1<<<4096, 256, 0, stream>>>(z, W1p, b1, h1);
  k23_gemm<0><<<512, 512, 131072, stream>>>(h1, W2tp, b2, W3, nullptr, gp2);
  k23_gemm<1><<<512, 512, 131072, stream>>>(gp2, W2c, nullptr, nullptr, h1, h1);
  k1_h1<<<4096, 256, 0, stream>>>(z, Wf1p, bf1, gp2);   // f1 -> gp2 buffer
  k4_gemm<<<512, 512, 0, stream>>>(h1, gp2, W1s, Wf2p, bf2, out);
}